// Round 9
// baseline (192.930 us; speedup 1.0000x reference)
//
#include <hip/hip_runtime.h>

#define BATCH   2048
#define DIM     512
#define DB_N    50000
#define TOPK    5
#define PADN    50176       // 392 tiles of 128
#define NCHUNK  28          // 14 tiles (1792 cols)/chunk; grid 8*28=224 blocks = 1/CU single pass
#define CTILES  14
#define CCOLS   1792
#define KSTEPS  56          // CTILES * 4 K-steps (BK=128 over DIM=512)
#define BM      256
#define BN      128
#define NFIN    12

typedef float f32x4 __attribute__((ext_vector_type(4)));
typedef long long i64;

__device__ __forceinline__ void async16(const void* g, void* l) {
    __builtin_amdgcn_global_load_lds(
        (const __attribute__((address_space(1))) unsigned int*)g,
        (__attribute__((address_space(3))) unsigned int*)l, 16, 0, 0);
}

// monotone float -> u32 (order-preserving for all finite values)
__device__ __forceinline__ unsigned sortbits(float v) {
    const int u = __float_as_int(v);
    return (unsigned)(u ^ ((u >> 31) | 0x80000000));
}

// ============ convert: L2-normalize, scale x16, fp8 e4m3, k-chunk (BK=128) + 16B-unit swizzle ======
// row r, k-bytes [kb*128 + w*16, +16) stored at byte ((kb*NROWS + r)*8 + (w ^ (r&7)))*16.
// Linear 16B DMA preserves unit order; ds_read XORs the unit index to recover k-order.
template<int NROWS>
__global__ void convert_kernel(const float* __restrict__ src, unsigned char* __restrict__ dst,
                               float* __restrict__ invp, int nreal) {
    const int r    = blockIdx.x * 4 + (threadIdx.x >> 6);
    const int lane = threadIdx.x & 63;
    float4 a = {0,0,0,0}, b = {0,0,0,0};
    float ss = 0.f;
    if (r < nreal) {
        const float* row = src + (size_t)r * DIM;
        a = *(const float4*)(row + lane * 8);
        b = *(const float4*)(row + lane * 8 + 4);
        ss = a.x*a.x + a.y*a.y + a.z*a.z + a.w*a.w
           + b.x*b.x + b.y*b.y + b.z*b.z + b.w*b.w;
    }
    #pragma unroll
    for (int off = 1; off < 64; off <<= 1) ss += __shfl_xor(ss, off);
    const float inv = 1.0f / fmaxf(sqrtf(ss), 1e-12f);
    const float s16 = inv * 16.0f;
    int lo = __builtin_amdgcn_cvt_pk_fp8_f32(a.x * s16, a.y * s16, 0, false);
    lo     = __builtin_amdgcn_cvt_pk_fp8_f32(a.z * s16, a.w * s16, lo, true);
    int hi = __builtin_amdgcn_cvt_pk_fp8_f32(b.x * s16, b.y * s16, 0, false);
    hi     = __builtin_amdgcn_cvt_pk_fp8_f32(b.z * s16, b.w * s16, hi, true);
    // this lane covers k in [lane*8, +8): unit u = lane>>1, kb = u>>3, w = u&7
    const int kb = lane >> 4;
    const int w  = (lane >> 1) & 7;
    int2 u2; u2.x = lo; u2.y = hi;
    *(int2*)(dst + ((size_t)kb * NROWS + r) * 128 + ((w ^ (r & 7)) << 4) + ((lane & 1) << 3)) = u2;
    if (invp && lane == 0) invp[r] = inv;
}

// ============ fused sim GEMM: 256x128 tile, 8 waves (4Mx2N, 64x64 each), quadrant phases, ==========
// ============ triple-buffer depth-2 prefetch, counted vmcnt(6), per-lane key top-2 ================
__global__ __launch_bounds__(512, 1) void sim_topk_kernel(
    const unsigned char* __restrict__ hzf, const unsigned char* __restrict__ dbzf,
    unsigned* __restrict__ pc) {

    __shared__ __align__(16) unsigned char As[3][BM * 128];   // 3 x 32KB
    __shared__ __align__(16) unsigned char Bs[3][BN * 128];   // 3 x 16KB
    __shared__ unsigned mrg[4][2][64][TOPK];                  // 10KB  -> total 157,696 B

    const int tid  = threadIdx.x;
    const int lane = tid & 63;
    const int l15  = lane & 15;
    const int lhi  = lane >> 4;
    const int wid  = tid >> 6;
    const int wm   = wid >> 1;            // 0..3 (64-row band)
    const int wn   = wid & 1;             // 0..1 (64-col half)
    const int mc   = blockIdx.x % NCHUNK;
    const int rb   = blockIdx.x / NCHUNK; // 0..7
    const int c0   = mc * CCOLS;

    // per-lane top-2 keys for each of this lane's 16 owned rows (q = mf*4+i)
    unsigned k0[16], k1[16];
    #pragma unroll
    for (int q = 0; q < 16; ++q) { k0[q] = 0u; k1[q] = 0u; }

    // stage K-step s (kb = s&3, tile t = s>>2) into buffer s%3; 6 x 16B DMA per thread
    auto STAGE = [&](int s) {
        const int buf = s % 3;
        const int kb  = s & 3;
        const int t   = s >> 2;
        const unsigned char* ga = hzf + ((size_t)kb * BATCH + (size_t)rb * BM) * 128;
        const unsigned char* gb = dbzf + ((size_t)kb * PADN + (size_t)(c0 + t * BN)) * 128;
        #pragma unroll
        for (int j = 0; j < 4; ++j)
            async16(ga + tid * 16 + j * 8192, &As[buf][tid * 16 + j * 8192]);
        #pragma unroll
        for (int j = 0; j < 2; ++j)
            async16(gb + tid * 16 + j * 8192, &Bs[buf][tid * 16 + j * 8192]);
    };

    // ds_read helpers: fragment (row r) for k-slot ks: byte = r*128 + ((sub^(r&7))<<4) + c8
    const int s2 = lhi >> 1;
    const int c8 = (lhi & 1) << 3;

    f32x4 acc[4][4];
    #pragma unroll
    for (int mf = 0; mf < 4; ++mf)
        #pragma unroll
        for (int nf = 0; nf < 4; ++nf) acc[mf][nf] = (f32x4){0.f, 0.f, 0.f, 0.f};

    STAGE(0);
    STAGE(1);

    #pragma unroll 1
    for (int s = 0; s < KSTEPS; ++s) {
        if (s == KSTEPS - 1) { asm volatile("s_waitcnt vmcnt(0)" ::: "memory"); }
        else                 { asm volatile("s_waitcnt vmcnt(6)" ::: "memory"); }
        __builtin_amdgcn_s_barrier();           // all waves' step-s DMAs complete & prior reads done
        __builtin_amdgcn_sched_barrier(0);
        if (s + 2 < KSTEPS) STAGE(s + 2);       // depth-2 prefetch into buf[(s+2)%3]

        const unsigned char* ta = As[s % 3];
        const unsigned char* tb = Bs[s % 3];

        i64 a0[8], a1[8], b0[8], b1[8];
        // ---- phase 0: LDA0 (mf 0-1) + LDB0 (nf 0-1); MFMA quadrant (mf0-1 x nf0-1) ----
        #pragma unroll
        for (int mf = 0; mf < 2; ++mf)
            #pragma unroll
            for (int ks = 0; ks < 4; ++ks) {
                const int r = wm * 64 + mf * 16 + l15;
                a0[mf * 4 + ks] = *(const i64*)(ta + r * 128 + (((ks * 2 + s2) ^ (r & 7)) << 4) + c8);
            }
        #pragma unroll
        for (int nf = 0; nf < 2; ++nf)
            #pragma unroll
            for (int ks = 0; ks < 4; ++ks) {
                const int r = wn * 64 + nf * 16 + l15;
                b0[nf * 4 + ks] = *(const i64*)(tb + r * 128 + (((ks * 2 + s2) ^ (r & 7)) << 4) + c8);
            }
        asm volatile("s_waitcnt lgkmcnt(0)" ::: "memory");
        __builtin_amdgcn_sched_barrier(0);
        __builtin_amdgcn_s_setprio(1);
        #pragma unroll
        for (int mf = 0; mf < 2; ++mf)
            #pragma unroll
            for (int nf = 0; nf < 2; ++nf)
                #pragma unroll
                for (int ks = 0; ks < 4; ++ks)
                    acc[mf][nf] = __builtin_amdgcn_mfma_f32_16x16x32_fp8_fp8(
                        a0[mf * 4 + ks], b0[nf * 4 + ks], acc[mf][nf], 0, 0, 0);
        __builtin_amdgcn_s_setprio(0);
        __builtin_amdgcn_sched_barrier(0);

        // ---- phase 1: LDB1 (nf 2-3); MFMA quadrant (mf0-1 x nf2-3), reuse a0 ----
        #pragma unroll
        for (int nf = 0; nf < 2; ++nf)
            #pragma unroll
            for (int ks = 0; ks < 4; ++ks) {
                const int r = wn * 64 + (nf + 2) * 16 + l15;
                b1[nf * 4 + ks] = *(const i64*)(tb + r * 128 + (((ks * 2 + s2) ^ (r & 7)) << 4) + c8);
            }
        asm volatile("s_waitcnt lgkmcnt(0)" ::: "memory");
        __builtin_amdgcn_sched_barrier(0);
        __builtin_amdgcn_s_setprio(1);
        #pragma unroll
        for (int mf = 0; mf < 2; ++mf)
            #pragma unroll
            for (int nf = 0; nf < 2; ++nf)
                #pragma unroll
                for (int ks = 0; ks < 4; ++ks)
                    acc[mf][nf + 2] = __builtin_amdgcn_mfma_f32_16x16x32_fp8_fp8(
                        a0[mf * 4 + ks], b1[nf * 4 + ks], acc[mf][nf + 2], 0, 0, 0);
        __builtin_amdgcn_s_setprio(0);
        __builtin_amdgcn_sched_barrier(0);

        // ---- phase 2: LDA1 (mf 2-3); MFMA quadrant (mf2-3 x nf2-3), reuse b1 ----
        #pragma unroll
        for (int mf = 0; mf < 2; ++mf)
            #pragma unroll
            for (int ks = 0; ks < 4; ++ks) {
                const int r = wm * 64 + (mf + 2) * 16 + l15;
                a1[mf * 4 + ks] = *(const i64*)(ta + r * 128 + (((ks * 2 + s2) ^ (r & 7)) << 4) + c8);
            }
        asm volatile("s_waitcnt lgkmcnt(0)" ::: "memory");
        __builtin_amdgcn_sched_barrier(0);
        __builtin_amdgcn_s_setprio(1);
        #pragma unroll
        for (int mf = 0; mf < 2; ++mf)
            #pragma unroll
            for (int nf = 0; nf < 2; ++nf)
                #pragma unroll
                for (int ks = 0; ks < 4; ++ks)
                    acc[mf + 2][nf + 2] = __builtin_amdgcn_mfma_f32_16x16x32_fp8_fp8(
                        a1[mf * 4 + ks], b1[nf * 4 + ks], acc[mf + 2][nf + 2], 0, 0, 0);
        __builtin_amdgcn_s_setprio(0);
        __builtin_amdgcn_sched_barrier(0);

        // ---- phase 3: MFMA quadrant (mf2-3 x nf0-1), reuse a1, b0 ----
        __builtin_amdgcn_s_setprio(1);
        #pragma unroll
        for (int mf = 0; mf < 2; ++mf)
            #pragma unroll
            for (int nf = 0; nf < 2; ++nf)
                #pragma unroll
                for (int ks = 0; ks < 4; ++ks)
                    acc[mf + 2][nf] = __builtin_amdgcn_mfma_f32_16x16x32_fp8_fp8(
                        a1[mf * 4 + ks], b0[nf * 4 + ks], acc[mf + 2][nf], 0, 0, 0);
        __builtin_amdgcn_s_setprio(0);
        __builtin_amdgcn_sched_barrier(0);

        // ---- tile boundary: harvest acc into per-lane top-2 keys; re-zero ----
        if ((s & 3) == 3) {
            const int tc = c0 + (s >> 2) * BN;
            #pragma unroll
            for (int nf = 0; nf < 4; ++nf) {
                const int  gcol  = tc + wn * 64 + nf * 16 + l15;
                const bool valid = gcol < DB_N;
                #pragma unroll
                for (int mf = 0; mf < 4; ++mf)
                    #pragma unroll
                    for (int i = 0; i < 4; ++i) {
                        const int q = mf * 4 + i;
                        const unsigned key = valid
                            ? ((sortbits(acc[mf][nf][i]) & 0xFFFF0000u) | (unsigned)gcol) : 0u;
                        const unsigned hi2 = key > k0[q] ? key   : k0[q];
                        const unsigned lo2 = key > k0[q] ? k0[q] : key;
                        k1[q] = lo2 > k1[q] ? lo2 : k1[q];
                        k0[q] = hi2;
                        acc[mf][nf][i] = 0.f;
                    }
            }
        }
    }

    // ---- once per chunk: per-row top-5 extract within each wave's 64-col half ----
    #pragma unroll
    for (int mf = 0; mf < 4; ++mf)
        #pragma unroll
        for (int i = 0; i < 4; ++i) {
            const int q = mf * 4 + i;
            unsigned a0k = k0[q], a1k = k1[q];
            #pragma unroll
            for (int it = 0; it < TOPK; ++it) {
                unsigned w = a0k;
                #pragma unroll
                for (int sh = 1; sh < 16; sh <<= 1) {
                    const unsigned o = (unsigned)__shfl_xor((int)w, sh);
                    w = o > w ? o : w;
                }
                const bool own = (a0k == w) && (w != 0u);
                a0k = own ? a1k : a0k;
                a1k = own ? 0u : a1k;
                if (l15 == q) mrg[wm][wn][mf * 16 + lhi * 4 + i][it] = w;
            }
        }
    __syncthreads();

    // ---- merge 2 col-halves -> exact chunk top-5 per row; write packed keys ----
    if (wn == 0) {
        unsigned bv[TOPK] = {0u, 0u, 0u, 0u, 0u};
        #pragma unroll
        for (int qq = 0; qq < 2; ++qq)
            #pragma unroll
            for (int j = 0; j < TOPK; ++j) {
                const unsigned u = mrg[wm][qq][lane][j];
                #pragma unroll
                for (int k = TOPK - 1; k >= 1; --k) {
                    const bool gt  = u > bv[k];
                    const bool gtp = u > bv[k - 1];
                    bv[k] = gt ? (gtp ? bv[k - 1] : u) : bv[k];
                }
                if (u > bv[0]) bv[0] = u;
            }
        const int row = rb * BM + wm * 64 + lane;
        #pragma unroll
        for (int j = 0; j < TOPK; ++j)
            pc[((size_t)row * NCHUNK + mc) * TOPK + j] = bv[j];
    }
}

// ============ finalize: top-12 of 140 keys, EXACT fp32 refine, top-5 + softmax + blend ============
__global__ void finalize_kernel(const float* __restrict__ h, const float* __restrict__ db,
                                const float* __restrict__ alpha_p,
                                const unsigned* __restrict__ pc,
                                const float* __restrict__ inv_db,
                                float* __restrict__ out) {
    const int b    = blockIdx.x;
    const int tid  = threadIdx.x;
    const int lane = tid & 63;
    const int wv   = tid >> 6;
    const int NC   = NCHUNK * TOPK;   // 140

    __shared__ int   fid[NFIN];
    __shared__ float fsim[NFIN];
    __shared__ float invh_s;
    __shared__ float mu_s[TOPK];
    __shared__ int   id_s[TOPK];

    if (wv == 0) {
        const unsigned* cp = pc + (size_t)b * NC;
        unsigned v[3];
        #pragma unroll
        for (int j = 0; j < 3; ++j) {
            const int c = lane + j * 64;
            v[j] = (c < NC) ? cp[c] : 0u;
        }
        for (int it = 0; it < NFIN; ++it) {
            unsigned m = v[0];
            #pragma unroll
            for (int j = 1; j < 3; ++j) m = v[j] > m ? v[j] : m;
            #pragma unroll
            for (int sh = 1; sh < 64; sh <<= 1) {
                const unsigned o = (unsigned)__shfl_xor((int)m, sh);
                m = o > m ? o : m;
            }
            if (lane == 0) {
                int gi = (int)(m & 0xFFFFu);
                fid[it] = gi < DB_N ? gi : DB_N - 1;
            }
            #pragma unroll
            for (int j = 0; j < 3; ++j) if (v[j] == m) v[j] = 0u;
        }
    } else if (wv == 1) {
        const float* hr = h + (size_t)b * DIM;
        const float4 a = *(const float4*)(hr + lane * 8);
        const float4 c = *(const float4*)(hr + lane * 8 + 4);
        float ss = a.x*a.x + a.y*a.y + a.z*a.z + a.w*a.w
                 + c.x*c.x + c.y*c.y + c.z*c.z + c.w*c.w;
        #pragma unroll
        for (int off = 1; off < 64; off <<= 1) ss += __shfl_xor(ss, off);
        if (lane == 0) invh_s = 1.0f / fmaxf(sqrtf(ss), 1e-12f);
    }
    __syncthreads();

    const float* hr = h + (size_t)b * DIM;
    for (int f = wv; f < NFIN; f += 4) {
        const int gi = fid[f];
        const float* dr = db + (size_t)gi * DIM;
        const float4 ha = *(const float4*)(hr + lane * 8);
        const float4 hb = *(const float4*)(hr + lane * 8 + 4);
        const float4 da = *(const float4*)(dr + lane * 8);
        const float4 dc = *(const float4*)(dr + lane * 8 + 4);
        float d = ha.x*da.x + ha.y*da.y + ha.z*da.z + ha.w*da.w
                + hb.x*dc.x + hb.y*dc.y + hb.z*dc.z + hb.w*dc.w;
        #pragma unroll
        for (int off = 1; off < 64; off <<= 1) d += __shfl_xor(d, off);
        if (lane == 0) fsim[f] = d * invh_s * inv_db[gi];
    }
    __syncthreads();

    if (tid == 0) {
        bool used[NFIN];
        #pragma unroll
        for (int j = 0; j < NFIN; ++j) used[j] = false;
        float bv[TOPK]; int bi[TOPK];
        for (int it = 0; it < TOPK; ++it) {
            float m = -3.0e38f; int mj = 0, mi = 0x7fffffff;
            for (int j = 0; j < NFIN; ++j) {
                if (used[j]) continue;
                if (fsim[j] > m || (fsim[j] == m && fid[j] < mi)) {
                    m = fsim[j]; mj = j; mi = fid[j];
                }
            }
            used[mj] = true; bv[it] = m; bi[it] = mi;
        }
        float ssum = 0.f, w[TOPK];
        #pragma unroll
        for (int j = 0; j < TOPK; ++j) { w[j] = expf(bv[j] - bv[0]); ssum += w[j]; }
        #pragma unroll
        for (int j = 0; j < TOPK; ++j) { mu_s[j] = w[j] / ssum; id_s[j] = bi[j]; }
    }
    __syncthreads();

    const float a = 1.0f / (1.0f + expf(-alpha_p[0]));
    for (int d = tid; d < DIM; d += 256) {
        float r = 0.f;
        #pragma unroll
        for (int j = 0; j < TOPK; ++j) r += mu_s[j] * db[(size_t)id_s[j] * DIM + d];
        out[(size_t)b * DIM + d] = a * h[(size_t)b * DIM + d] + (1.f - a) * r;
    }
}

extern "C" void kernel_launch(void* const* d_in, const int* in_sizes, int n_in,
                              void* d_out, int out_size, void* d_ws, size_t ws_size,
                              hipStream_t stream) {
    const float* h     = (const float*)d_in[0];
    const float* db    = (const float*)d_in[1];
    const float* alpha = (const float*)d_in[2];
    float* out = (float*)d_out;

    const size_t dbzf_bytes = (size_t)PADN * DIM;        // 25,690,112
    const size_t hzf_bytes  = (size_t)BATCH * DIM;       //  1,048,576
    const size_t inv_bytes  = (size_t)PADN * 4;          //    200,704
    // pc: 2048*28*5*4 = 1,146,880  -> total ~28.1MB

    unsigned char* dbzf  = (unsigned char*)d_ws;
    unsigned char* hzf   = (unsigned char*)d_ws + dbzf_bytes;
    float*         invdb = (float*)((char*)d_ws + dbzf_bytes + hzf_bytes);
    unsigned*      pc    = (unsigned*)((char*)d_ws + dbzf_bytes + hzf_bytes + inv_bytes);

    convert_kernel<PADN><<<PADN / 4, 256, 0, stream>>>(db, dbzf, invdb, DB_N);
    convert_kernel<BATCH><<<BATCH / 4, 256, 0, stream>>>(h, hzf, nullptr, BATCH);
    sim_topk_kernel<<<8 * NCHUNK, 512, 0, stream>>>(hzf, dbzf, pc);
    finalize_kernel<<<BATCH, 256, 0, stream>>>(h, db, alpha, pc, invdb, out);
}

// Round 10
// 167.767 us; speedup vs baseline: 1.1500x; 1.1500x over previous
//
#include <hip/hip_runtime.h>

#define BATCH   2048
#define DIM     512
#define DB_N    50000
#define TOPK    5
#define PADN    50176       // 392 tiles of 128
#define NCHUNK  56          // 7 tiles (896 cols)/chunk; 56%8==0 -> chunk pins to one XCD L2
#define CTILES  7
#define CCOLS   896
#define TM      128
#define TN      128
#define NFIN    12

typedef float f32x4 __attribute__((ext_vector_type(4)));
typedef long long i64;
typedef long long i64x2 __attribute__((ext_vector_type(2)));

__device__ __forceinline__ void async16(const void* g, void* l) {
    __builtin_amdgcn_global_load_lds(
        (const __attribute__((address_space(1))) unsigned int*)g,
        (__attribute__((address_space(3))) unsigned int*)l, 16, 0, 0);
}

// monotone float -> u32 (order-preserving for all finite values)
__device__ __forceinline__ unsigned sortbits(float v) {
    const int u = __float_as_int(v);
    return (unsigned)(u ^ ((u >> 31) | 0x80000000));
}

// ============ convert: L2-normalize, scale x16, fp8 e4m3, kb-chunk (128B) + lane-major order ======
// Row r's 128 bytes (k = kb*128 + [0,128)) are stored so that the 8 bytes MFMA-lane (l15,lhi)
// needs for k-slot ks sit at unit u = lhi*2 + (ks>>1) (16B), half = ks&1, XOR-swizzled:
//   byte' = ((u ^ (r&7)) << 4) + half*8.
// One ds_read_b128 at unit (lhi*2+j)^ (r&7) yields the operands for ks=2j (low 8B) and 2j+1 (high).
template<int NROWS>
__global__ void convert_kernel(const float* __restrict__ src, unsigned char* __restrict__ dst,
                               float* __restrict__ invp, int nreal) {
    const int r    = blockIdx.x * 4 + (threadIdx.x >> 6);
    const int lane = threadIdx.x & 63;
    float4 a = {0,0,0,0}, b = {0,0,0,0};
    float ss = 0.f;
    if (r < nreal) {
        const float* row = src + (size_t)r * DIM;
        a = *(const float4*)(row + lane * 8);
        b = *(const float4*)(row + lane * 8 + 4);
        ss = a.x*a.x + a.y*a.y + a.z*a.z + a.w*a.w
           + b.x*b.x + b.y*b.y + b.z*b.z + b.w*b.w;
    }
    #pragma unroll
    for (int off = 1; off < 64; off <<= 1) ss += __shfl_xor(ss, off);
    const float inv = 1.0f / fmaxf(sqrtf(ss), 1e-12f);
    const float s16 = inv * 16.0f;
    int lo = __builtin_amdgcn_cvt_pk_fp8_f32(a.x * s16, a.y * s16, 0, false);
    lo     = __builtin_amdgcn_cvt_pk_fp8_f32(a.z * s16, a.w * s16, lo, true);
    int hi = __builtin_amdgcn_cvt_pk_fp8_f32(b.x * s16, b.y * s16, 0, false);
    hi     = __builtin_amdgcn_cvt_pk_fp8_f32(b.z * s16, b.w * s16, hi, true);
    // this lane holds k-global [lane*8, +8): kb = lane>>4; within kb: q = lane&15, k' = q*8
    const int kb   = lane >> 4;
    const int q    = lane & 15;
    const int ks   = q >> 2;          // k' / 32
    const int lh   = q & 3;           // (k' / 8) % 4
    const int u    = lh * 2 + (ks >> 1);
    const int half = ks & 1;
    int2 u2; u2.x = lo; u2.y = hi;
    *(int2*)(dst + ((size_t)kb * NROWS + r) * 128 + ((u ^ (r & 7)) << 4) + (half << 3)) = u2;
    if (invp && lane == 0) invp[r] = inv;
}

// ============ fused sim GEMM (fp8, 128x128, BK=128) + per-lane key top-2; counted-vmcnt, b128 reads =
__global__ __launch_bounds__(512, 4) void sim_topk_kernel(
    const unsigned char* __restrict__ hzf, const unsigned char* __restrict__ dbzf,
    unsigned* __restrict__ pc) {

    __shared__ __align__(16) unsigned char As[2][TM * 128];   // 2 x 16KB
    __shared__ __align__(16) unsigned char Bs[2][TN * 128];   // 2 x 16KB
    __shared__ unsigned mrg[2][4][64][TOPK];                  // 10KB

    const int tid  = threadIdx.x;
    const int lane = tid & 63;
    const int l15  = lane & 15;
    const int lhi  = lane >> 4;
    const int wid  = tid >> 6;
    const int uw   = __builtin_amdgcn_readfirstlane(wid);
    const int wm   = wid >> 2;            // 0..1 (row half)
    const int wn   = wid & 3;             // 0..3 (col quarter)
    const int mc   = blockIdx.x % NCHUNK; // chunk; rb-siblings share XCD (56%8==0)
    const int rb   = blockIdx.x / NCHUNK; // 0..15
    const int c0   = mc * CCOLS;

    // per-lane top-2 keys for each of this lane's 16 owned rows (q = mf*4+i)
    unsigned k0[16], k1[16];
    #pragma unroll
    for (int q = 0; q < 16; ++q) { k0[q] = 0u; k1[q] = 0u; }

    // per-lane ds_read bases (mf/nf enter as constant byte offsets mf*2048):
    // row&7 == l15&7 for all frags (16 | mf*16, 8 | wm*64, wn*32)
    const int x7 = l15 & 7;
    const int aoff0 = (wm * 64 + l15) * 128 + ((((lhi << 1) | 0) ^ x7) << 4);
    const int aoff1 = (wm * 64 + l15) * 128 + ((((lhi << 1) | 1) ^ x7) << 4);
    const int boff0 = (wn * 32 + l15) * 128 + ((((lhi << 1) | 0) ^ x7) << 4);
    const int boff1 = (wn * 32 + l15) * 128 + ((((lhi << 1) | 1) ^ x7) << 4);

    auto STAGE = [&](int buf, int t, int kb) {
        const unsigned char* ga = hzf +
            (((size_t)kb * BATCH + (size_t)rb * TM) * 8 + uw * 128 + lane) * 16;
        const unsigned char* gb = dbzf +
            (((size_t)kb * PADN + (size_t)(c0 + t * TN)) * 8 + uw * 128 + lane) * 16;
        async16(ga,        &As[buf][uw * 2048]);
        async16(ga + 1024, &As[buf][uw * 2048 + 1024]);
        async16(gb,        &Bs[buf][uw * 2048]);
        async16(gb + 1024, &Bs[buf][uw * 2048 + 1024]);
    };

    f32x4 acc[4][2];

    STAGE(0, 0, 0);

    int p = 0;
    #pragma unroll 1
    for (int t = 0; t < CTILES; ++t) {
        #pragma unroll
        for (int mf = 0; mf < 4; ++mf)
            #pragma unroll
            for (int nf = 0; nf < 2; ++nf) acc[mf][nf] = (f32x4){0.f, 0.f, 0.f, 0.f};

        #pragma unroll
        for (int kb = 0; kb < 4; ++kb) {
            // issue next-phase prefetch, then wait only for THIS phase's 4 loads;
            // the 4 prefetch loads stay in flight across the barrier (T4)
            const int np = p + 1;
            if (np < CTILES * 4) {
                STAGE(np & 1, np >> 2, np & 3);
                asm volatile("s_waitcnt vmcnt(4)" ::: "memory");
            } else {
                asm volatile("s_waitcnt vmcnt(0)" ::: "memory");
            }
            __builtin_amdgcn_s_barrier();            // barrier A: phase-p data visible
            __builtin_amdgcn_sched_barrier(0);

            const unsigned char* ta = As[p & 1];
            const unsigned char* tb = Bs[p & 1];
            #pragma unroll
            for (int j = 0; j < 2; ++j) {
                const int ao = j ? aoff1 : aoff0;
                const int bo = j ? boff1 : boff0;
                i64x2 av[4], bv[2];
                #pragma unroll
                for (int mf = 0; mf < 4; ++mf)
                    av[mf] = *(const i64x2*)(ta + ao + mf * 2048);
                #pragma unroll
                for (int nf = 0; nf < 2; ++nf)
                    bv[nf] = *(const i64x2*)(tb + bo + nf * 2048);
                __builtin_amdgcn_s_setprio(1);
                #pragma unroll
                for (int hf = 0; hf < 2; ++hf)
                    #pragma unroll
                    for (int mf = 0; mf < 4; ++mf)
                        #pragma unroll
                        for (int nf = 0; nf < 2; ++nf)
                            acc[mf][nf] = __builtin_amdgcn_mfma_f32_16x16x32_fp8_fp8(
                                av[mf][hf], bv[nf][hf], acc[mf][nf], 0, 0, 0);
                __builtin_amdgcn_s_setprio(0);
            }
            __builtin_amdgcn_sched_barrier(0);
            __builtin_amdgcn_s_barrier();            // barrier B: all reads done; buf reusable
            ++p;
        }

        // ---- per-tile epilogue: branchless per-lane top-2 key update (registers only) ----
        const int tc = c0 + t * TN;
        #pragma unroll
        for (int nf = 0; nf < 2; ++nf) {
            const int  gcol  = tc + wn * 32 + nf * 16 + l15;
            const bool valid = gcol < DB_N;
            #pragma unroll
            for (int mf = 0; mf < 4; ++mf)
                #pragma unroll
                for (int i = 0; i < 4; ++i) {
                    const int q = mf * 4 + i;
                    const unsigned key = valid
                        ? ((sortbits(acc[mf][nf][i]) & 0xFFFF0000u) | (unsigned)gcol) : 0u;
                    const unsigned hi2 = key > k0[q] ? key   : k0[q];
                    const unsigned lo2 = key > k0[q] ? k0[q] : key;
                    k1[q] = lo2 > k1[q] ? lo2 : k1[q];
                    k0[q] = hi2;
                }
        }
    }

    // ---- once per chunk: per-row top-5 extract within each wave's col quarter ----
    #pragma unroll
    for (int mf = 0; mf < 4; ++mf)
        #pragma unroll
        for (int i = 0; i < 4; ++i) {
            const int q = mf * 4 + i;
            unsigned a0 = k0[q], a1 = k1[q];
            #pragma unroll
            for (int it = 0; it < TOPK; ++it) {
                unsigned w = a0;
                #pragma unroll
                for (int sh = 1; sh < 16; sh <<= 1) {
                    const unsigned o = (unsigned)__shfl_xor((int)w, sh);
                    w = o > w ? o : w;
                }
                const bool own = (a0 == w) && (w != 0u);
                a0 = own ? a1 : a0;
                a1 = own ? 0u : a1;
                if (l15 == q) mrg[wm][wn][mf * 16 + lhi * 4 + i][it] = w;
            }
        }
    __syncthreads();

    // ---- merge 4 col-quarters -> exact chunk top-5 per row; write packed keys ----
    if (wn == 0) {
        unsigned bv[TOPK] = {0u, 0u, 0u, 0u, 0u};
        #pragma unroll
        for (int qq = 0; qq < 4; ++qq)
            #pragma unroll
            for (int j = 0; j < TOPK; ++j) {
                const unsigned u = mrg[wm][qq][lane][j];
                #pragma unroll
                for (int k = TOPK - 1; k >= 1; --k) {
                    const bool gt  = u > bv[k];
                    const bool gtp = u > bv[k - 1];
                    bv[k] = gt ? (gtp ? bv[k - 1] : u) : bv[k];
                }
                if (u > bv[0]) bv[0] = u;
            }
        const int row = rb * TM + wm * 64 + lane;
        #pragma unroll
        for (int j = 0; j < TOPK; ++j)
            pc[((size_t)row * NCHUNK + mc) * TOPK + j] = bv[j];
    }
}

// ============ finalize: top-12 of 280 keys, EXACT fp32 refine, top-5 + softmax + blend ============
__global__ void finalize_kernel(const float* __restrict__ h, const float* __restrict__ db,
                                const float* __restrict__ alpha_p,
                                const unsigned* __restrict__ pc,
                                const float* __restrict__ inv_db,
                                float* __restrict__ out) {
    const int b    = blockIdx.x;
    const int tid  = threadIdx.x;
    const int lane = tid & 63;
    const int wv   = tid >> 6;
    const int NC   = NCHUNK * TOPK;   // 280

    __shared__ int   fid[NFIN];
    __shared__ float fsim[NFIN];
    __shared__ float invh_s;
    __shared__ float mu_s[TOPK];
    __shared__ int   id_s[TOPK];

    if (wv == 0) {
        const unsigned* cp = pc + (size_t)b * NC;
        unsigned v[5];
        #pragma unroll
        for (int j = 0; j < 5; ++j) {
            const int c = lane + j * 64;
            v[j] = (c < NC) ? cp[c] : 0u;
        }
        for (int it = 0; it < NFIN; ++it) {
            unsigned m = v[0];
            #pragma unroll
            for (int j = 1; j < 5; ++j) m = v[j] > m ? v[j] : m;
            #pragma unroll
            for (int sh = 1; sh < 64; sh <<= 1) {
                const unsigned o = (unsigned)__shfl_xor((int)m, sh);
                m = o > m ? o : m;
            }
            if (lane == 0) {
                int gi = (int)(m & 0xFFFFu);
                fid[it] = gi < DB_N ? gi : DB_N - 1;
            }
            #pragma unroll
            for (int j = 0; j < 5; ++j) if (v[j] == m) v[j] = 0u;
        }
    } else if (wv == 1) {
        const float* hr = h + (size_t)b * DIM;
        const float4 a = *(const float4*)(hr + lane * 8);
        const float4 c = *(const float4*)(hr + lane * 8 + 4);
        float ss = a.x*a.x + a.y*a.y + a.z*a.z + a.w*a.w
                 + c.x*c.x + c.y*c.y + c.z*c.z + c.w*c.w;
        #pragma unroll
        for (int off = 1; off < 64; off <<= 1) ss += __shfl_xor(ss, off);
        if (lane == 0) invh_s = 1.0f / fmaxf(sqrtf(ss), 1e-12f);
    }
    __syncthreads();

    const float* hr = h + (size_t)b * DIM;
    for (int f = wv; f < NFIN; f += 4) {
        const int gi = fid[f];
        const float* dr = db + (size_t)gi * DIM;
        const float4 ha = *(const float4*)(hr + lane * 8);
        const float4 hb = *(const float4*)(hr + lane * 8 + 4);
        const float4 da = *(const float4*)(dr + lane * 8);
        const float4 dc = *(const float4*)(dr + lane * 8 + 4);
        float d = ha.x*da.x + ha.y*da.y + ha.z*da.z + ha.w*da.w
                + hb.x*dc.x + hb.y*dc.y + hb.z*dc.z + hb.w*dc.w;
        #pragma unroll
        for (int off = 1; off < 64; off <<= 1) d += __shfl_xor(d, off);
        if (lane == 0) fsim[f] = d * invh_s * inv_db[gi];
    }
    __syncthreads();

    if (tid == 0) {
        bool used[NFIN];
        #pragma unroll
        for (int j = 0; j < NFIN; ++j) used[j] = false;
        float bv[TOPK]; int bi[TOPK];
        for (int it = 0; it < TOPK; ++it) {
            float m = -3.0e38f; int mj = 0, mi = 0x7fffffff;
            for (int j = 0; j < NFIN; ++j) {
                if (used[j]) continue;
                if (fsim[j] > m || (fsim[j] == m && fid[j] < mi)) {
                    m = fsim[j]; mj = j; mi = fid[j];
                }
            }
            used[mj] = true; bv[it] = m; bi[it] = mi;
        }
        float ssum = 0.f, w[TOPK];
        #pragma unroll
        for (int j = 0; j < TOPK; ++j) { w[j] = expf(bv[j] - bv[0]); ssum += w[j]; }
        #pragma unroll
        for (int j = 0; j < TOPK; ++j) { mu_s[j] = w[j] / ssum; id_s[j] = bi[j]; }
    }
    __syncthreads();

    const float a = 1.0f / (1.0f + expf(-alpha_p[0]));
    for (int d = tid; d < DIM; d += 256) {
        float r = 0.f;
        #pragma unroll
        for (int j = 0; j < TOPK; ++j) r += mu_s[j] * db[(size_t)id_s[j] * DIM + d];
        out[(size_t)b * DIM + d] = a * h[(size_t)b * DIM + d] + (1.f - a) * r;
    }
}

extern "C" void kernel_launch(void* const* d_in, const int* in_sizes, int n_in,
                              void* d_out, int out_size, void* d_ws, size_t ws_size,
                              hipStream_t stream) {
    const float* h     = (const float*)d_in[0];
    const float* db    = (const float*)d_in[1];
    const float* alpha = (const float*)d_in[2];
    float* out = (float*)d_out;

    const size_t dbzf_bytes = (size_t)PADN * DIM;        // 25,690,112
    const size_t hzf_bytes  = (size_t)BATCH * DIM;       //  1,048,576
    const size_t inv_bytes  = (size_t)PADN * 4;          //    200,704
    // pc: 2048*56*5*4 = 2,293,760  -> total ~29.2MB

    unsigned char* dbzf  = (unsigned char*)d_ws;
    unsigned char* hzf   = (unsigned char*)d_ws + dbzf_bytes;
    float*         invdb = (float*)((char*)d_ws + dbzf_bytes + hzf_bytes);
    unsigned*      pc    = (unsigned*)((char*)d_ws + dbzf_bytes + hzf_bytes + inv_bytes);

    convert_kernel<PADN><<<PADN / 4, 256, 0, stream>>>(db, dbzf, invdb, DB_N);
    convert_kernel<BATCH><<<BATCH / 4, 256, 0, stream>>>(h, hzf, nullptr, BATCH);
    sim_topk_kernel<<<16 * NCHUNK, 512, 0, stream>>>(hzf, dbzf, pc);
    finalize_kernel<<<BATCH, 256, 0, stream>>>(h, db, alpha, pc, invdb, out);
}